// Round 1
// baseline (345.071 us; speedup 1.0000x reference)
//
#include <hip/hip_runtime.h>
#include <hip/hip_bf16.h>

typedef unsigned int u32;
typedef unsigned short u16;
typedef short short8 __attribute__((ext_vector_type(8)));
typedef float f32x4 __attribute__((ext_vector_type(4)));

#define R_ 32
#define KEYS_PER_B 2048     // 4 wavegroups * 32 relations * 16 rows
#define SORT_STRIDE 1024    // fixed per-chunk slots in sorted[] (mean 767, +9 sigma)
#define CAP 16              // per-wave per-relation buffered edge gathers

static __device__ __forceinline__ u16 f2bf(float f) {
  u32 u = __float_as_uint(f);
  u = (u + 0x7FFFu + ((u >> 16) & 1u)) >> 16;   // RNE
  return (u16)u;
}
static __device__ __forceinline__ u32 pk2(float a, float b) {
  __hip_bfloat162 h2 = __float22bfloat162_rn(make_float2(a, b));
  union { __hip_bfloat162 h; u32 u; } cv; cv.h = h2; return cv.u;
}

// ---- fused: x fp32->bf16 convert  +  W/W_root pack into MFMA B-fragment order ----
__global__ void k_pre(const float* __restrict__ x, const float* __restrict__ W,
                      const float* __restrict__ Wroot, u16* __restrict__ xb,
                      u16* __restrict__ wp, u16* __restrict__ wrootp,
                      int n4, int convNB) {
  if ((int)blockIdx.x < convNB) {
    int i = blockIdx.x * 256 + threadIdx.x;
    if (i >= n4) return;
    const float4 f = ((const float4*)x)[i];
    u32 lo = (u32)f2bf(f.x) | ((u32)f2bf(f.y) << 16);
    u32 hi = (u32)f2bf(f.z) | ((u32)f2bf(f.w) << 16);
    ((uint2*)xb)[i] = make_uint2(lo, hi);
  } else {
    int tid = (blockIdx.x - convNB) * 256 + threadIdx.x;
    if (tid >= 33 * 2048) return;
    int lane = tid & 63;
    int ks = (tid >> 6) & 3;
    int ct = (tid >> 8) & 7;
    int rr = tid >> 11;
    int i0 = ks * 32 + (lane >> 4) * 8;
    int o  = ct * 16 + (lane & 15);
    const float* src = (rr < 32) ? (W + (size_t)rr * (128 * 128)) : Wroot;
    u16* dst = (rr < 32) ? (wp + ((size_t)((rr * 8 + ct) * 4 + ks) * 64 + lane) * 8)
                         : (wrootp + ((size_t)((ct * 4 + ks) * 64 + lane)) * 8);
#pragma unroll
    for (int j = 0; j < 8; ++j) dst[j] = f2bf(src[(size_t)(i0 + j) * 128 + o]);
  }
}

static __device__ __forceinline__ int sort_key(int tgt, int r) {
  return (tgt >> 6) * KEYS_PER_B + ((tgt >> 4) & 3) * 512 + r * 16 + (tgt & 15);
}

// ---- histogram of sort keys ----
__global__ void k_hist(const int* __restrict__ ei, const int* __restrict__ et,
                       int* __restrict__ hist, int E) {
  int e = blockIdx.x * 256 + threadIdx.x;
  if (e >= E) return;
  atomicAdd(hist + sort_key(ei[E + e], et[e]), 1);
}

// ---- per-chunk exclusive scan (chunk = 2048 keys = one batch) ----
__global__ __launch_bounds__(256) void k_scan_local(const int* __restrict__ hist,
                                                    int* __restrict__ offs) {
  __shared__ int wsum[4];
  int b = blockIdx.x, t = threadIdx.x;
  size_t base = (size_t)b * KEYS_PER_B + (size_t)t * 8;
  int4 a = *(const int4*)(hist + base);
  int4 c = *(const int4*)(hist + base + 4);
  int v[8] = {a.x, a.y, a.z, a.w, c.x, c.y, c.z, c.w};
  int s = 0;
#pragma unroll
  for (int i = 0; i < 8; ++i) s += v[i];
  int lane = t & 63, w = t >> 6;
  int x = s;
#pragma unroll
  for (int off = 1; off < 64; off <<= 1) {
    int y = __shfl_up(x, off);
    if (lane >= off) x += y;
  }
  if (lane == 63) wsum[w] = x;
  __syncthreads();
  int wb = 0;
  for (int i = 0; i < w; ++i) wb += wsum[i];
  int ex = wb + x - s;
  int o[8];
#pragma unroll
  for (int i = 0; i < 8; ++i) { o[i] = ex; ex += v[i]; }
  *(int4*)(offs + base) = make_int4(o[0], o[1], o[2], o[3]);
  *(int4*)(offs + base + 4) = make_int4(o[4], o[5], o[6], o[7]);
}

// ---- scatter; offs[key] becomes per-key chunk-local END; sorted = src | row64<<16 ----
__global__ void k_scatter(const int* __restrict__ ei, const int* __restrict__ et,
                          int* __restrict__ offs, u32* __restrict__ sorted, int E) {
  int e = blockIdx.x * 256 + threadIdx.x;
  if (e >= E) return;
  int src = ei[e];
  int tgt = ei[E + e];
  int r = et[e];
  int p = atomicAdd(offs + sort_key(tgt, r), 1);
  if (p < SORT_STRIDE)
    sorted[(size_t)(tgt >> 6) * SORT_STRIDE + p] = (u32)src | ((u32)(tgt & 63) << 16);
}

// ---- main batch kernel (relation-split across blocks) ----
// Block (b, q): nodes b*64..b*64+63, relations q*nRel..q*nRel+nRel-1.
// q==0 additionally does the root GEMM and adds bias. Output is a RAW partial
// plane (no relu); k_score merges planes and applies relu.
// Wave w owns rows w*16..w*16+15. Its edges for relation r are CONTIGUOUS in
// sorted (key = batch,wavegroup,rel,row). Per relation:
//   build(r): zero own aggb rows; consume prefetched xv[] with run-detection
//   barrier
//   phaseA(r): issue ev+xv gathers for r+1 (in flight across GEMM),
//              prefetch offs end for r+2, GEMM(r) from aggb + wp
//   barrier
__global__ __launch_bounds__(256) void k_batch(
    const u16* __restrict__ xb, const u16* __restrict__ wp, const u16* __restrict__ wrootp,
    const float* __restrict__ bias, const u32* __restrict__ sorted,
    const int* __restrict__ offs, float* __restrict__ hplanes, int N, int shift) {
  __shared__ u16 aggb[64 * 136];   // 17.4 KB
  const int q = blockIdx.x & ((1 << shift) - 1);
  const int b = blockIdx.x >> shift;
  const int nRel = R_ >> shift;
  const int r0 = q * nRel;
  const int t = threadIdx.x;
  const int lane = t & 63, w = t >> 6;
  const int m = lane & 15, qq = lane >> 4;
  const int nb = b * 64;
  const int keyBase = b * KEYS_PER_B;
  const int wkBase = keyBase + w * 512;
  const u32* srt = sorted + (size_t)b * SORT_STRIDE;

  const int nEdge = offs[keyBase + KEYS_PER_B - 1];
  const int clampP = (nEdge > 0) ? nEdge - 1 : 0;
  int sCur = (w == 0 && r0 == 0) ? 0 : offs[wkBase + r0 * 16 - 1];  // start of rel r0
  int eCur = offs[wkBase + r0 * 16 + 15];                           // end of rel r0
  int eNext = offs[wkBase + r0 * 16 + 31];                          // end of rel r0+1

  // prologue: issue gathers for relation r0 (overlap root GEMM for q==0)
  u32 ev;
  {
    int pc = sCur + m;
    if (pc > clampP) pc = clampP;
    ev = srt[pc];
  }
  u32 xv[CAP];
  {
    const int nB = min(eCur - sCur, CAP);
#pragma unroll
    for (int j = 0; j < CAP; ++j) {
      if (j < nB) {
        int e = __builtin_amdgcn_readlane((int)ev, j);
        xv[j] = *(const u32*)(xb + (size_t)(e & 0xFFFF) * 128 + 2 * lane);
      }
    }
  }

  const short8 zero8 = {0, 0, 0, 0, 0, 0, 0, 0};
  f32x4 acc[4][2];
#pragma unroll
  for (int rt = 0; rt < 4; ++rt)
#pragma unroll
    for (int c = 0; c < 2; ++c) acc[rt][c] = (f32x4){0.f, 0.f, 0.f, 0.f};
  const int wct0 = w * 2;

  // root GEMM: acc += x_batch @ W_root (only the q==0 plane)
  if (q == 0) {
#pragma unroll
    for (int ks = 0; ks < 4; ++ks) {
      const int kb = ks * 32 + qq * 8;
      short8 af[4];
#pragma unroll
      for (int rt = 0; rt < 4; ++rt) {
        int node = nb + rt * 16 + m;
        af[rt] = (node < N) ? *(const short8*)(xb + (size_t)node * 128 + kb) : zero8;
      }
#pragma unroll
      for (int c = 0; c < 2; ++c) {
        short8 bf = *(const short8*)(wrootp + ((size_t)(((wct0 + c) * 4 + ks) * 64 + lane)) * 8);
#pragma unroll
        for (int rt = 0; rt < 4; ++rt)
          acc[rt][c] = __builtin_amdgcn_mfma_f32_16x16x32_bf16(af[rt], bf, acc[rt][c], 0, 0, 0);
      }
    }
  }
  __syncthreads();

  for (int ri = 0; ri < nRel; ++ri) {
    const int r = r0 + ri;
    // ---- build(r): zero own rows, consume buffer with run detection ----
#pragma unroll
    for (int rr = 0; rr < 16; ++rr)
      *(u32*)(aggb + (size_t)(w * 16 + rr) * 136 + 2 * lane) = 0;

    {
      const int nB = min(eCur - sCur, CAP);
      int curRow = -1, rc = 0;
      float v0 = 0.f, v1 = 0.f;
#pragma unroll
      for (int j = 0; j < CAP; ++j) {
        if (j < nB) {
          int e = __builtin_amdgcn_readlane((int)ev, j);
          int tl = (e >> 16) & 63;
          if (tl != curRow) {
            if (rc > 0) {
              float sc = 1.0f / (float)rc;
              *(u32*)(aggb + (size_t)curRow * 136 + 2 * lane) = pk2(v0 * sc, v1 * sc);
            }
            curRow = tl; v0 = 0.f; v1 = 0.f; rc = 0;
          }
          v0 += __uint_as_float(xv[j] << 16);
          v1 += __uint_as_float(xv[j] & 0xFFFF0000u);
          ++rc;
        }
      }
      // rare overflow tail (cnt > CAP): serial loads
      for (int p = sCur + CAP; p < eCur; ++p) {
        u32 e = srt[p];
        u32 xvv = *(const u32*)(xb + (size_t)(e & 0xFFFFu) * 128 + 2 * lane);
        int tl = (int)((e >> 16) & 63);
        if (tl != curRow) {
          if (rc > 0) {
            float sc = 1.0f / (float)rc;
            *(u32*)(aggb + (size_t)curRow * 136 + 2 * lane) = pk2(v0 * sc, v1 * sc);
          }
          curRow = tl; v0 = 0.f; v1 = 0.f; rc = 0;
        }
        v0 += __uint_as_float(xvv << 16);
        v1 += __uint_as_float(xvv & 0xFFFF0000u);
        ++rc;
      }
      if (rc > 0) {
        float sc = 1.0f / (float)rc;
        *(u32*)(aggb + (size_t)curRow * 136 + 2 * lane) = pk2(v0 * sc, v1 * sc);
      }
    }
    __syncthreads();

    // ---- phase A: issue gathers for r+1, prefetch bounds for r+2, GEMM(r) ----
    if (ri < nRel - 1) {
      const int sN = eCur;
      const int eN = eNext;
      int pc = sN + m;
      if (pc > clampP) pc = clampP;
      ev = srt[pc];
      const int nBn = min(eN - sN, CAP);
#pragma unroll
      for (int j = 0; j < CAP; ++j) {
        if (j < nBn) {
          int e = __builtin_amdgcn_readlane((int)ev, j);
          xv[j] = *(const u32*)(xb + (size_t)(e & 0xFFFF) * 128 + 2 * lane);
        }
      }
      if (ri < nRel - 2) eNext = offs[wkBase + (r0 + ri + 2) * 16 + 15];
      sCur = sN; eCur = eN;
    }

    // GEMM(r): acc += agg @ W[r]
    short8 bfr[4][2];
#pragma unroll
    for (int ks = 0; ks < 4; ++ks)
#pragma unroll
      for (int c = 0; c < 2; ++c)
        bfr[ks][c] = *(const short8*)(wp + ((size_t)(((r * 8 + wct0 + c) * 4 + ks) * 64 + lane)) * 8);
#pragma unroll
    for (int ks = 0; ks < 4; ++ks) {
      const int kb = ks * 32 + qq * 8;
      short8 af[4];
#pragma unroll
      for (int rt = 0; rt < 4; ++rt)
        af[rt] = *(const short8*)(aggb + (size_t)(rt * 16 + m) * 136 + kb);
#pragma unroll
      for (int c = 0; c < 2; ++c)
#pragma unroll
        for (int rt = 0; rt < 4; ++rt)
          acc[rt][c] = __builtin_amdgcn_mfma_f32_16x16x32_bf16(af[rt], bfr[ks][c], acc[rt][c], 0, 0, 0);
    }
    __syncthreads();
  }

  // ---- epilogue: (+bias for q==0) store RAW partial plane (fp32, no relu) ----
  float* hq = hplanes + (size_t)q * (size_t)N * 128;
#pragma unroll
  for (int c = 0; c < 2; ++c) {
    const int col = (wct0 + c) * 16 + m;
    const float bv = (q == 0) ? bias[col] : 0.f;
#pragma unroll
    for (int rt = 0; rt < 4; ++rt) {
#pragma unroll
      for (int g = 0; g < 4; ++g) {
        const int row = nb + rt * 16 + qq * 4 + g;
        if (row < N) hq[(size_t)row * 128 + col] = acc[rt][c][g] + bv;
      }
    }
  }
}

// ---- DistMult scoring: one wave per triplet; merge S partial planes + relu ----
__global__ void k_score(const float* __restrict__ hp, int planeElems, int S,
                        const float* __restrict__ rel_emb,
                        const int* __restrict__ head, const int* __restrict__ tail,
                        const int* __restrict__ rel, float* __restrict__ out, int T) {
  int lane = threadIdx.x & 63, w = threadIdx.x >> 6;
  int gid = blockIdx.x * 4 + w;
  if (gid >= T) return;
  const size_t ho = (size_t)head[gid] * 128 + 2 * lane;
  const size_t to = (size_t)tail[gid] * 128 + 2 * lane;
  float hx = 0.f, hy = 0.f, tx = 0.f, ty = 0.f;
  for (int s = 0; s < S; ++s) {
    const float2 a = *(const float2*)(hp + (size_t)s * planeElems + ho);
    const float2 c = *(const float2*)(hp + (size_t)s * planeElems + to);
    hx += a.x; hy += a.y; tx += c.x; ty += c.y;
  }
  hx = hx > 0.f ? hx : 0.f;
  hy = hy > 0.f ? hy : 0.f;
  tx = tx > 0.f ? tx : 0.f;
  ty = ty > 0.f ? ty : 0.f;
  const float2 r2 = *(const float2*)(rel_emb + (size_t)rel[gid] * 128 + 2 * lane);
  float s = hx * r2.x * tx + hy * r2.y * ty;
#pragma unroll
  for (int off = 32; off > 0; off >>= 1) s += __shfl_down(s, off);
  if (lane == 0) out[gid] = s;
}

extern "C" void kernel_launch(void* const* d_in, const int* in_sizes, int n_in,
                              void* d_out, int out_size, void* d_ws, size_t ws_size,
                              hipStream_t stream) {
  const float* x     = (const float*)d_in[0];
  const float* W     = (const float*)d_in[1];
  const float* Wroot = (const float*)d_in[2];
  const float* bias  = (const float*)d_in[3];
  const float* relE  = (const float*)d_in[4];
  const int* ei      = (const int*)d_in[5];
  const int* et      = (const int*)d_in[6];
  const int* headI   = (const int*)d_in[7];
  const int* tailI   = (const int*)d_in[8];
  const int* relI    = (const int*)d_in[9];
  float* out = (float*)d_out;

  const int N = in_sizes[0] / 128;   // 50000
  const int E = in_sizes[6];         // 600000
  const int T = in_sizes[7];         // 8192
  const int NB = (N + 63) >> 6;      // 782
  const int NKEYS = NB * KEYS_PER_B;

  char* p = (char*)d_ws;
  auto alloc = [&](size_t bytes) -> void* {
    void* r = (void*)p;
    p += (bytes + 255) & ~(size_t)255;
    return r;
  };
  u16* xb     = (u16*)alloc((size_t)N * 128 * 2);        // 12.8 MB
  u16* wp     = (u16*)alloc((size_t)32 * 2048 * 8 * 2);  // 1 MB
  u16* wrootp = (u16*)alloc((size_t)2048 * 8 * 2);
  int* hist   = (int*)alloc((size_t)NKEYS * 4);          // 6.4 MB
  int* offs   = (int*)alloc((size_t)NKEYS * 4);          // 6.4 MB
  u32* sorted = (u32*)alloc((size_t)NB * SORT_STRIDE * 4); // 3.2 MB

  // relation-split factor: as many partial-h planes as the workspace affords
  const size_t planeBytes = (size_t)N * 128 * 4;         // 25.6 MB
  const size_t usedSoFar = (size_t)(p - (char*)d_ws);
  int shift = 0;
  if (ws_size >= usedSoFar + 4 * planeBytes + 1024) shift = 2;
  else if (ws_size >= usedSoFar + 2 * planeBytes + 1024) shift = 1;
  const int SPLIT = 1 << shift;
  float* planes = (float*)alloc((size_t)SPLIT * planeBytes);

  const int n4 = N * 128 / 4;
  const int convNB = (n4 + 255) / 256;
  const int packNB = (33 * 2048 + 255) / 256;

  hipMemsetAsync(hist, 0, (size_t)NKEYS * 4, stream);
  k_pre<<<convNB + packNB, 256, 0, stream>>>(x, W, Wroot, xb, wp, wrootp, n4, convNB);
  k_hist<<<(E + 255) / 256, 256, 0, stream>>>(ei, et, hist, E);
  k_scan_local<<<NB, 256, 0, stream>>>(hist, offs);
  k_scatter<<<(E + 255) / 256, 256, 0, stream>>>(ei, et, offs, sorted, E);
  k_batch<<<NB << shift, 256, 0, stream>>>(xb, wp, wrootp, bias, sorted, offs, planes, N, shift);
  k_score<<<(T + 3) / 4, 256, 0, stream>>>(planes, N * 128, SPLIT, relE, headI, tailI, relI, out, T);
}